// Round 1
// baseline (115.842 us; speedup 1.0000x reference)
//
#include <hip/hip_runtime.h>

#define BLOCK 256
#define MPT 8                          // query points per thread
#define PTS_PER_BLOCK (BLOCK * MPT)    // 2048
#define NCHUNK 16                      // candidate chunks per direction
#define BATCH 4
#define NPTS 8192
#define CHUNK (NPTS / NCHUNK)          // 512 candidates staged per block

// dir 0: candidates = gt, queries = rec  (min over n for each m  -> loss_1)
// dir 1: candidates = rec, queries = gt  (min over m for each n  -> loss_2)
__global__ __launch_bounds__(BLOCK) void chamfer_min_kernel(
    const float* __restrict__ gt, const float* __restrict__ rec,
    unsigned int* __restrict__ minbuf)
{
    int zc  = blockIdx.z;
    int dir = zc >> 2;        // BATCH == 4
    int b   = zc & 3;
    const float* X = (dir == 0) ? gt : rec;   // candidates
    const float* Y = (dir == 0) ? rec : gt;   // queries
    X += (size_t)b * NPTS * 3;
    Y += (size_t)b * NPTS * 3;

    __shared__ float4 xs[CHUNK];
    int c0 = blockIdx.y * CHUNK;
    for (int t = threadIdx.x; t < CHUNK; t += BLOCK) {
        float x0 = X[(c0 + t) * 3 + 0];
        float x1 = X[(c0 + t) * 3 + 1];
        float x2 = X[(c0 + t) * 3 + 2];
        xs[t] = make_float4(x0, x1, x2, x0 * x0 + x1 * x1 + x2 * x2);
    }
    __syncthreads();

    int q0 = blockIdx.x * PTS_PER_BLOCK + threadIdx.x;
    float ny0[MPT], ny1[MPT], ny2[MPT], yy[MPT], mn[MPT];
#pragma unroll
    for (int p = 0; p < MPT; ++p) {
        int q = q0 + p * BLOCK;
        float y0 = Y[q * 3 + 0], y1 = Y[q * 3 + 1], y2 = Y[q * 3 + 2];
        ny0[p] = -2.0f * y0;
        ny1[p] = -2.0f * y1;
        ny2[p] = -2.0f * y2;
        yy[p]  = y0 * y0 + y1 * y1 + y2 * y2;
        mn[p]  = 3.0e38f;
    }

    for (int j = 0; j < CHUNK; j += 2) {
        float4 ca = xs[j];
        float4 cb = xs[j + 1];
#pragma unroll
        for (int p = 0; p < MPT; ++p) {
            float ta = fmaf(ca.x, ny0[p], ca.w);
            ta = fmaf(ca.y, ny1[p], ta);
            ta = fmaf(ca.z, ny2[p], ta);
            float tb = fmaf(cb.x, ny0[p], cb.w);
            tb = fmaf(cb.y, ny1[p], tb);
            tb = fmaf(cb.z, ny2[p], tb);
            mn[p] = fminf(mn[p], fminf(ta, tb));
        }
    }

    unsigned int* mb = minbuf + (size_t)(dir * BATCH + b) * NPTS;
#pragma unroll
    for (int p = 0; p < MPT; ++p) {
        // add back ||y||^2, clamp to >=1e-10 (commutes with min), atomicMin on bits
        float v = fmaxf(mn[p] + yy[p], 1e-10f);
        atomicMin(&mb[q0 + p * BLOCK], __float_as_uint(v));
    }
}

__global__ __launch_bounds__(1024) void chamfer_reduce_kernel(
    const unsigned int* __restrict__ minbuf, float* __restrict__ out)
{
    const int TOT  = 2 * BATCH * NPTS;   // 65536
    const int HALF = BATCH * NPTS;       // 32768
    int tid = threadIdx.x;
    float s0 = 0.f, s1 = 0.f;
    for (int i = tid; i < HALF; i += 1024) s0 += __uint_as_float(minbuf[i]);
    for (int i = HALF + tid; i < TOT; i += 1024) s1 += __uint_as_float(minbuf[i]);
#pragma unroll
    for (int off = 32; off > 0; off >>= 1) {
        s0 += __shfl_down(s0, off, 64);
        s1 += __shfl_down(s1, off, 64);
    }
    __shared__ float w0[16], w1[16];
    int wid = tid >> 6, lane = tid & 63;
    if (lane == 0) { w0[wid] = s0; w1[wid] = s1; }
    __syncthreads();
    if (tid == 0) {
        float a = 0.f, c = 0.f;
        for (int i = 0; i < 16; ++i) { a += w0[i]; c += w1[i]; }
        out[0] = (a / (float)HALF + c / (float)HALF) * 1000.0f;
    }
}

extern "C" void kernel_launch(void* const* d_in, const int* in_sizes, int n_in,
                              void* d_out, int out_size, void* d_ws, size_t ws_size,
                              hipStream_t stream) {
    const float* gt  = (const float*)d_in[0];
    const float* rec = (const float*)d_in[1];
    unsigned int* minbuf = (unsigned int*)d_ws;

    // init minbuf to 0x7F7F7F7F (= 3.39e38 as float) — identity for uint-min
    hipMemsetAsync(minbuf, 0x7F, (size_t)2 * BATCH * NPTS * sizeof(unsigned int), stream);

    dim3 grid(NPTS / PTS_PER_BLOCK, NCHUNK, 2 * BATCH);  // 4 x 16 x 8 = 512 blocks
    chamfer_min_kernel<<<grid, BLOCK, 0, stream>>>(gt, rec, minbuf);
    chamfer_reduce_kernel<<<1, 1024, 0, stream>>>(minbuf, (float*)d_out);
}